// Round 5
// baseline (139.811 us; speedup 1.0000x reference)
//
#include <hip/hip_runtime.h>

#define T 2000
#define K1N 2496         // 39*64
#define K2 4992          // hi/lo duplicated K (bf16 shorts per W1t row)
#define TLA 8            // hops t-tile (250 x 8 = 2000 exact)
#define MAXNZ 24
#define NBLK 250

using short8 = __attribute__((ext_vector_type(8))) short;
using floatx4 = __attribute__((ext_vector_type(4))) float;

__device__ __forceinline__ unsigned bf16_rne(float v) {
    unsigned u = __float_as_uint(v);
    return (u + 0x7FFFu + ((u >> 16) & 1u)) >> 16;
}
__device__ __forceinline__ unsigned packhl(float w) {
    unsigned hi = bf16_rne(w);
    float r = w - __uint_as_float(hi << 16);   // exact
    unsigned lo = bf16_rne(r);
    return (hi & 0xFFFFu) | (lo << 16);
}

// ============ K1: A_hat + 3 hops ONCE for all nodes -> Fg[39][T][8]; W1 pack =========
// 250 blocks x 8 t-cols, zero overlap (verbatim from R2/R4's passing version).
__global__ __launch_bounds__(256) void hops(const float* __restrict__ x,
        const int* __restrict__ ei, float* __restrict__ Fg,
        const float* __restrict__ W1, unsigned* __restrict__ W1t,
        float* __restrict__ out) {
    __shared__ float ah[1560];
    __shared__ float2 alist[39 * MAXNZ];
    __shared__ int nnzr[40];
    __shared__ float bufA[78 * TLA];
    __shared__ float bufB[78 * TLA];
    __shared__ float feat[39 * TLA * 8];   // [node][tt][8]
    int tid = threadIdx.x;
    int bl = blockIdx.x;                   // 0..249
    int ts = bl * TLA;

    if (bl == 0 && tid < 36) out[tid] = 0.f;

    for (int u = tid; u < 1521; u += 256) ah[u] = 0.f;
    __syncthreads();
    if (tid < 156) atomicAdd(&ah[ei[156 + tid] * 39 + ei[tid]], 1.f);
    __syncthreads();
    if (tid < 39) {
        float d = 0.f;
        for (int u = 0; u < 39; ++u) d += ah[tid * 39 + u];
        ah[1521 + tid] = (d > 0.f) ? (1.f / sqrtf(d)) : 0.f;
    }
    __syncthreads();
    for (int u = tid; u < 1521; u += 256) {
        int i = u / 39, j = u - i * 39;
        ah[u] = (ah[1521 + i] * ah[u]) * ah[1521 + j];
    }
    __syncthreads();
    if (tid < 39) {
        int cnt = 0;
        for (int m = 0; m < 39; ++m) {
            float v = ah[tid * 39 + m];
            if (v != 0.f && cnt < MAXNZ) {
                alist[tid * MAXNZ + cnt] = make_float2(v, __int_as_float((2 * m) * TLA * 4));
                ++cnt;
            }
        }
        nnzr[tid] = cnt;
    }
    __syncthreads();

    for (int e = tid; e < 78 * TLA; e += 256) {
        int r = e / TLA, tt = e - r * TLA;
        bufA[r * TLA + tt] = x[r * T + ts + tt];
    }
    __syncthreads();

    // f0/f1 + h1 (bufA -> bufB)
    for (int e = tid; e < 78 * TLA; e += 256) {
        int r = e / TLA, tt = e - r * TLA;
        feat[((r >> 1) * TLA + tt) * 8 + (r & 1)] = bufA[r * TLA + tt];
    }
    for (int e = tid; e < 78; e += 256) {
        int r = e, ii = r >> 1, c = r & 1;
        float acc[8];
        #pragma unroll
        for (int u = 0; u < 8; ++u) acc[u] = 0.f;
        int nz = nnzr[ii];
        const float2* lp = &alist[ii * MAXNZ];
        int cg = c * (TLA * 4);
        for (int q = 0; q < nz; ++q) {
            float2 av = lp[q];
            const float* xp = (const float*)((const char*)bufA + (__float_as_int(av.y) + cg));
            float a = av.x;
            float4 x0 = *(const float4*)xp;
            float4 x1 = *(const float4*)(xp + 4);
            acc[0] += a * x0.x; acc[1] += a * x0.y; acc[2] += a * x0.z; acc[3] += a * x0.w;
            acc[4] += a * x1.x; acc[5] += a * x1.y; acc[6] += a * x1.z; acc[7] += a * x1.w;
        }
        float* dp = &bufB[r * TLA];
        *(float4*)dp = *(float4*)&acc[0];
        *(float4*)(dp + 4) = *(float4*)&acc[4];
    }
    __syncthreads();

    // f2/f3 + h2 (bufB -> bufA)
    for (int e = tid; e < 78 * TLA; e += 256) {
        int r = e / TLA, tt = e - r * TLA;
        feat[((r >> 1) * TLA + tt) * 8 + 2 + (r & 1)] = bufB[r * TLA + tt];
    }
    for (int e = tid; e < 78; e += 256) {
        int r = e, ii = r >> 1, c = r & 1;
        float acc[8];
        #pragma unroll
        for (int u = 0; u < 8; ++u) acc[u] = 0.f;
        int nz = nnzr[ii];
        const float2* lp = &alist[ii * MAXNZ];
        int cg = c * (TLA * 4);
        for (int q = 0; q < nz; ++q) {
            float2 av = lp[q];
            const float* xp = (const float*)((const char*)bufB + (__float_as_int(av.y) + cg));
            float a = av.x;
            float4 x0 = *(const float4*)xp;
            float4 x1 = *(const float4*)(xp + 4);
            acc[0] += a * x0.x; acc[1] += a * x0.y; acc[2] += a * x0.z; acc[3] += a * x0.w;
            acc[4] += a * x1.x; acc[5] += a * x1.y; acc[6] += a * x1.z; acc[7] += a * x1.w;
        }
        float* dp = &bufA[r * TLA];
        *(float4*)dp = *(float4*)&acc[0];
        *(float4*)(dp + 4) = *(float4*)&acc[4];
    }
    __syncthreads();

    // f4/f5 + h3 (bufA -> feat[6+c])
    for (int e = tid; e < 78 * TLA; e += 256) {
        int r = e / TLA, tt = e - r * TLA;
        feat[((r >> 1) * TLA + tt) * 8 + 4 + (r & 1)] = bufA[r * TLA + tt];
    }
    for (int e = tid; e < 78; e += 256) {
        int r = e, ii = r >> 1, c = r & 1;
        float acc[8];
        #pragma unroll
        for (int u = 0; u < 8; ++u) acc[u] = 0.f;
        int nz = nnzr[ii];
        const float2* lp = &alist[ii * MAXNZ];
        int cg = c * (TLA * 4);
        for (int q = 0; q < nz; ++q) {
            float2 av = lp[q];
            const float* xp = (const float*)((const char*)bufA + (__float_as_int(av.y) + cg));
            float a = av.x;
            float4 x0 = *(const float4*)xp;
            float4 x1 = *(const float4*)(xp + 4);
            acc[0] += a * x0.x; acc[1] += a * x0.y; acc[2] += a * x0.z; acc[3] += a * x0.w;
            acc[4] += a * x1.x; acc[5] += a * x1.y; acc[6] += a * x1.z; acc[7] += a * x1.w;
        }
        #pragma unroll
        for (int u = 0; u < 8; ++u)
            feat[(ii * TLA + u) * 8 + 6 + c] = acc[u];
    }
    __syncthreads();

    for (int e = tid; e < 39 * TLA * 2; e += 256) {
        int idx = e >> 1, half = e & 1;
        int n = idx / TLA, tt = idx - n * TLA;
        *(float4*)&Fg[((size_t)n * T + ts + tt) * 8 + half * 4] =
            *(const float4*)&feat[idx * 8 + half * 4];
    }

    const int total = 128 * K1N;
    for (int f = bl * 256 + tid; f < total; f += NBLK * 256) {
        int k = f >> 7, jj = f & 127;
        W1t[jj * K1N + k] = packhl(W1[f]);
    }
}

// ============ K2: fused c1-scan + gemm1 MFMA, 512 threads ============================
// grid (63, 6). 512 threads: every one of the 416 channels gets its own scan thread
// (serial wall halves vs 256-thread 2-channel version); MFMA runs on 8 waves x 16 j.
__global__ __launch_bounds__(512) void scan_gemm1(
        const float* __restrict__ Fg, const float* __restrict__ Wc,
        const float* __restrict__ bc, const short* __restrict__ W1t,
        float* __restrict__ F1p) {
    __shared__ __align__(16) char smem[13312 + 23040];
    unsigned char* S2 = (unsigned char*)smem;      // [32][416] spike bytes
    float* FgL = (float*)(smem + 13312);           // 7 nodes x ncol x 8 (<=10752 B)
    short* As  = (short*)(smem + 13312);           // 32x72 (reuses FgL region)
    short* Ws  = (short*)(smem + 13312 + 4608);    // 128x72

    int tid = threadIdx.x;
    int bx = blockIdx.x, ks = blockIdx.y;
    int t0 = bx * 32;
    int hs = t0 - 16; if (hs < 0) hs = 0;
    int ncol = t0 + 32 - hs;               // 32 (bx=0) or 48
    int k0g = ks * 416;
    int nd0 = k0g >> 6;                    // slice spans exactly 7 nodes

    // ---- issue W1t prefetch early (latency hidden under scan) ----
    int kb2 = ks * 832;
    int jjv[2], kov[2];
    #pragma unroll
    for (int u = 0; u < 2; ++u) {
        int aid = u * 512 + tid;           // 1024 slots = 128 rows x 8 offsets
        jjv[u] = aid >> 3;
        kov[u] = (aid & 7) * 8;
    }
    short8 wr0 = *(const short8*)&W1t[jjv[0] * K2 + kb2 + kov[0]];
    short8 wr1 = *(const short8*)&W1t[jjv[1] * K2 + kb2 + kov[1]];

    // ---- stage Fg slice: 7 nodes x ncol x 8 ----
    for (int e = tid; e < 7 * ncol * 2; e += 512) {
        int idx = e >> 1, half = e & 1;
        int nl = idx / ncol, cc = idx - nl * ncol;
        int t = hs + cc;
        int gn = nd0 + nl;
        float4 v = make_float4(0.f, 0.f, 0.f, 0.f);
        if (gn < 39 && t < T)
            v = *(const float4*)&Fg[((size_t)gn * T + t) * 8 + half * 4];
        *(float4*)&FgL[(nl * ncol + cc) * 8 + half * 4] = v;
    }
    __syncthreads();

    // ---- scan 416 channels, exactly one per thread (identical FMA order to R4) ----
    {
        int cn = tid;
        if (cn < 416) {
            int gk = k0g + cn;
            int nl = (gk >> 6) - nd0;
            int j = gk & 63;
            float wv[8];
            #pragma unroll
            for (int q = 0; q < 8; ++q) wv[q] = Wc[q * 64 + j];
            float bias = bc[j];
            float m = 0.f, s = 0.f;
            const float* fb = &FgL[nl * ncol * 8];
            for (int cc = 0; cc < ncol; ++cc) {
                float4 a0 = *(const float4*)&fb[cc * 8];
                float4 a1 = *(const float4*)&fb[cc * 8 + 4];
                float acc = 0.f;
                acc += wv[0] * a0.x; acc += wv[1] * a0.y;
                acc += wv[2] * a0.z; acc += wv[3] * a0.w;
                acc += wv[4] * a1.x; acc += wv[5] * a1.y;
                acc += wv[6] * a1.z; acc += wv[7] * a1.w;
                float v = acc + bias;
                m = m * 0.2f * (1.f - s) + v;
                s = (m > 0.5f) ? 1.f : 0.f;
                int t = hs + cc;
                if (t >= t0) S2[(t - t0) * 416 + cn] = (unsigned char)(s != 0.f);
            }
        }
    }
    __syncthreads();   // S2 complete; FgL dead (As/Ws may now overwrite)

    // ---- MFMA loop: 13 chunks of 32 k; 8 waves x 16 j-cols ----
    int lane = tid & 63, wvi = tid >> 6;   // wvi 0..7
    int j0 = wvi * 16;
    int row = lane & 15, quad = lane >> 4;
    floatx4 a00 = {0.f, 0.f, 0.f, 0.f};
    floatx4 a10 = a00;
    int sm = tid >> 3, sb4 = (tid & 7) * 4;   // valid for tid<256
    for (int c = 0; c < 13; ++c) {
        if (tid < 256) {
            unsigned u4 = *(const unsigned*)&S2[sm * 416 + c * 32 + sb4];
            uint4 dd;
            dd.x = (u4 & 0x000000FFu) ? 0x3F803F80u : 0u;
            dd.y = (u4 & 0x0000FF00u) ? 0x3F803F80u : 0u;
            dd.z = (u4 & 0x00FF0000u) ? 0x3F803F80u : 0u;
            dd.w = (u4 & 0xFF000000u) ? 0x3F803F80u : 0u;
            *(uint4*)&As[sm * 72 + sb4 * 2] = dd;
        }
        *(short8*)&Ws[jjv[0] * 72 + kov[0]] = wr0;
        *(short8*)&Ws[jjv[1] * 72 + kov[1]] = wr1;
        __syncthreads();
        short8 wn0, wn1;
        if (c < 12) {
            wn0 = *(const short8*)&W1t[jjv[0] * K2 + kb2 + (c + 1) * 64 + kov[0]];
            wn1 = *(const short8*)&W1t[jjv[1] * K2 + kb2 + (c + 1) * 64 + kov[1]];
        }
        #pragma unroll
        for (int sh = 0; sh < 2; ++sh) {
            int k0 = sh * 32 + quad * 8;
            short8 fa0 = *(const short8*)&As[row * 72 + k0];
            short8 fa1 = *(const short8*)&As[(row + 16) * 72 + k0];
            short8 fb0 = *(const short8*)&Ws[(j0 + row) * 72 + k0];
            a00 = __builtin_amdgcn_mfma_f32_16x16x32_bf16(fa0, fb0, a00, 0, 0, 0);
            a10 = __builtin_amdgcn_mfma_f32_16x16x32_bf16(fa1, fb0, a10, 0, 0, 0);
        }
        __syncthreads();
        if (c < 12) { wr0 = wn0; wr1 = wn1; }
    }
    #pragma unroll
    for (int r = 0; r < 4; ++r) {
        int m0 = quad * 4 + r;
        int t = t0 + m0;
        if (t < T)
            F1p[t * 768 + ks * 128 + j0 + row] = a00[r];
        int t2 = t0 + 16 + m0;
        if (t2 < T)
            F1p[t2 * 768 + ks * 128 + j0 + row] = a10[r];
    }
}

// ============ K3: h1 scan (warm 16) + gemm2, t-tile 8, grid 250 ======================
__global__ __launch_bounds__(256) void h1_gemm2(const float* __restrict__ F1p,
        const float* __restrict__ b1, const float* __restrict__ W2,
        float* __restrict__ G2) {
    __shared__ float AT[128 * 8];
    int tid = threadIdx.x;
    int t0 = blockIdx.x * 8;
    if (tid < 128) {
        int n = tid;
        int hs = t0 - 16; if (hs < 0) hs = 0;
        float b = b1[n];
        float m = 0.f, s = 0.f;
        for (int tg = hs; tg < t0 + 8; tg += 4) {     // lengths 8/24: both %4==0
            float vb[4][6];
            #pragma unroll
            for (int u = 0; u < 4; ++u)
                #pragma unroll
                for (int q = 0; q < 6; ++q)
                    vb[u][q] = F1p[(tg + u) * 768 + q * 128 + n];
            #pragma unroll
            for (int u = 0; u < 4; ++u) {
                float v = 0.f;
                #pragma unroll
                for (int q = 0; q < 6; ++q) v += vb[u][q];
                v += b;
                m = m * 0.2f * (1.f - s) + v;
                s = (m > 0.5f) ? 1.f : 0.f;
                int t = tg + u;
                if (t >= t0) AT[n * 8 + (t - t0)] = s;
            }
        }
    }
    __syncthreads();
    int j = tid;
    float acc[8] = {0.f};
    #pragma unroll 4
    for (int k = 0; k < 128; ++k) {
        float w = W2[k * 256 + j];
        float4 q0 = *(const float4*)&AT[k * 8 + 0];
        float4 q1 = *(const float4*)&AT[k * 8 + 4];
        acc[0] += q0.x * w; acc[1] += q0.y * w; acc[2] += q0.z * w; acc[3] += q0.w * w;
        acc[4] += q1.x * w; acc[5] += q1.y * w; acc[6] += q1.z * w; acc[7] += q1.w * w;
    }
    #pragma unroll
    for (int tt = 0; tt < 8; ++tt) G2[(t0 + tt) * 256 + j] = acc[tt];
}

// ============ K4: tail, t-tile 10 (200 blocks), warm 25+25 unchanged =================
__global__ __launch_bounds__(256) void tail(const float* __restrict__ G2,
        const float* __restrict__ b2, const float* __restrict__ W3,
        const float* __restrict__ b3, float* __restrict__ out) {
    __shared__ float w3t[36 * 260];          // [jj][k] pad 260
    __shared__ unsigned char S2[36 * 260];   // [t][n] pad 260, rows <= 35
    __shared__ float G3[36 * 36];            // rows <= 35
    int tid = threadIdx.x;
    int t0 = blockIdx.x * 10;
    int gs = t0 - 25; if (gs < 0) gs = 0;
    int hs = gs - 25; if (hs < 0) hs = 0;
    int L3 = t0 + 10 - gs;                   // 10..35
    #pragma unroll
    for (int u = 0; u < 9; ++u) {
        int f = u * 1024 + tid * 4;
        float4 wq = *(const float4*)&W3[f];
        int k0 = f / 36, j0 = f - k0 * 36;
        float wv[4] = {wq.x, wq.y, wq.z, wq.w};
        #pragma unroll
        for (int q = 0; q < 4; ++q) {
            int k = (j0 + q >= 36) ? k0 + 1 : k0;
            int jj = (j0 + q >= 36) ? (j0 + q - 36) : (j0 + q);
            w3t[jj * 260 + k] = wv[q];
        }
    }
    {
        int n = tid;
        float b = b2[n];
        float m = 0.f, s = 0.f;
        for (int base = hs; base < t0 + 10; base += 10) {   // range length % 10 == 0
            float vb[10];
            #pragma unroll
            for (int u = 0; u < 10; ++u) vb[u] = G2[(base + u) * 256 + n];
            #pragma unroll
            for (int u = 0; u < 10; ++u) {
                float v = vb[u] + b;
                m = m * 0.2f * (1.f - s) + v;
                s = (m > 0.5f) ? 1.f : 0.f;
                int t = base + u;
                if (t >= gs) S2[(t - gs) * 260 + n] = (unsigned char)(s != 0.f);
            }
        }
    }
    __syncthreads();
    for (int e = tid; e < 36 * 9; e += 256) {
        int jj = e / 9, g = e - (e / 9) * 9;
        int tb = g * 4;
        if (tb >= L3) continue;
        float ac0 = 0.f, ac1 = 0.f, ac2 = 0.f, ac3 = 0.f;
        const unsigned char* r0 = &S2[tb * 260];
        for (int k = 0; k < 256; k += 4) {
            float4 w = *(const float4*)&w3t[jj * 260 + k];
            uchar4 q0 = *(const uchar4*)&r0[k];
            uchar4 q1 = *(const uchar4*)&r0[260 + k];
            uchar4 q2 = *(const uchar4*)&r0[520 + k];
            uchar4 q3 = *(const uchar4*)&r0[780 + k];
            ac0 += (float)q0.x * w.x + (float)q0.y * w.y + (float)q0.z * w.z + (float)q0.w * w.w;
            ac1 += (float)q1.x * w.x + (float)q1.y * w.y + (float)q1.z * w.z + (float)q1.w * w.w;
            ac2 += (float)q2.x * w.x + (float)q2.y * w.y + (float)q2.z * w.z + (float)q2.w * w.w;
            ac3 += (float)q3.x * w.x + (float)q3.y * w.y + (float)q3.z * w.z + (float)q3.w * w.w;
        }
        G3[tb * 36 + jj] = ac0;
        if (tb + 1 < L3) G3[(tb + 1) * 36 + jj] = ac1;
        if (tb + 2 < L3) G3[(tb + 2) * 36 + jj] = ac2;
        if (tb + 3 < L3) G3[(tb + 3) * 36 + jj] = ac3;
    }
    __syncthreads();
    if (tid < 36) {
        int n = tid;
        float b = b3[n];
        float m = 0.f, s = 0.f;
        int cnt = 0;
        for (int t = gs; t < t0 + 10; ++t) {
            float v = G3[(t - gs) * 36 + n] + b;
            m = m * 0.2f * (1.f - s) + v;
            s = (m > 0.5f) ? 1.f : 0.f;
            if (t >= t0) cnt += (s != 0.f) ? 1 : 0;
        }
        atomicAdd(&out[n], (float)cnt * 0.0005f);
    }
}

extern "C" void kernel_launch(void* const* d_in, const int* in_sizes, int n_in,
                              void* d_out, int out_size, void* d_ws, size_t ws_size,
                              hipStream_t stream) {
    const float* x  = (const float*)d_in[0];
    const int*   ei = (const int*)d_in[1];
    const float* Wc = (const float*)d_in[2];
    const float* bc = (const float*)d_in[3];
    const float* W1 = (const float*)d_in[4];
    const float* b1 = (const float*)d_in[5];
    const float* W2 = (const float*)d_in[6];
    const float* b2 = (const float*)d_in[7];
    const float* W3 = (const float*)d_in[8];
    const float* b3 = (const float*)d_in[9];
    float* out = (float*)d_out;

    float* w = (float*)d_ws;
    float* F1p = w;                       w += (size_t)T * 768;    // [t][6][128]
    float* G2  = w;                       w += (size_t)T * 256;
    float* Fg  = w;                       w += (size_t)39 * T * 8; // hop features
    unsigned* W1t = (unsigned*)w;         w += 128 * K1N;

    hops<<<NBLK, 256, 0, stream>>>(x, ei, Fg, W1, W1t, out);
    scan_gemm1<<<dim3(63, 6), 512, 0, stream>>>(Fg, Wc, bc, (const short*)W1t, F1p);
    h1_gemm2<<<250, 256, 0, stream>>>(F1p, b1, W2, G2);
    tail<<<200, 256, 0, stream>>>(G2, b2, W3, b3, out);
}

// Round 6
// 136.836 us; speedup vs baseline: 1.0217x; 1.0217x over previous
//
#include <hip/hip_runtime.h>

#define T 2000
#define K1N 2496         // 39*64
#define K2 4992          // hi/lo duplicated K (bf16 shorts per W1t row)
#define TLA 8            // hops t-tile (250 x 8 = 2000 exact)
#define MAXNZ 24
#define NBLK 250
#define S2P 420          // S2 row stride bytes (105 dwords, bank-stride 9: conflict-free)

using short8 = __attribute__((ext_vector_type(8))) short;
using floatx4 = __attribute__((ext_vector_type(4))) float;

__device__ __forceinline__ unsigned bf16_rne(float v) {
    unsigned u = __float_as_uint(v);
    return (u + 0x7FFFu + ((u >> 16) & 1u)) >> 16;
}
__device__ __forceinline__ unsigned packhl(float w) {
    unsigned hi = bf16_rne(w);
    float r = w - __uint_as_float(hi << 16);   // exact
    unsigned lo = bf16_rne(r);
    return (hi & 0xFFFFu) | (lo << 16);
}
// 4 spike bytes -> 8 bf16 shorts (hi/lo duplicated), bit-identical to the old As fill
__device__ __forceinline__ short8 spike8(unsigned u) {
    union { uint4 d; short8 s; } r;
    r.d.x = (u & 0x000000FFu) ? 0x3F803F80u : 0u;
    r.d.y = (u & 0x0000FF00u) ? 0x3F803F80u : 0u;
    r.d.z = (u & 0x00FF0000u) ? 0x3F803F80u : 0u;
    r.d.w = (u & 0xFF000000u) ? 0x3F803F80u : 0u;
    return r.s;
}

// ============ K1: A_hat + 3 hops ONCE for all nodes -> Fg[39][T][8]; W1 pack =========
// 250 blocks x 8 t-cols, zero overlap (verbatim R2/R4 passing version).
__global__ __launch_bounds__(256) void hops(const float* __restrict__ x,
        const int* __restrict__ ei, float* __restrict__ Fg,
        const float* __restrict__ W1, unsigned* __restrict__ W1t,
        float* __restrict__ out) {
    __shared__ float ah[1560];
    __shared__ float2 alist[39 * MAXNZ];
    __shared__ int nnzr[40];
    __shared__ float bufA[78 * TLA];
    __shared__ float bufB[78 * TLA];
    __shared__ float feat[39 * TLA * 8];   // [node][tt][8]
    int tid = threadIdx.x;
    int bl = blockIdx.x;                   // 0..249
    int ts = bl * TLA;

    if (bl == 0 && tid < 36) out[tid] = 0.f;

    for (int u = tid; u < 1521; u += 256) ah[u] = 0.f;
    __syncthreads();
    if (tid < 156) atomicAdd(&ah[ei[156 + tid] * 39 + ei[tid]], 1.f);
    __syncthreads();
    if (tid < 39) {
        float d = 0.f;
        for (int u = 0; u < 39; ++u) d += ah[tid * 39 + u];
        ah[1521 + tid] = (d > 0.f) ? (1.f / sqrtf(d)) : 0.f;
    }
    __syncthreads();
    for (int u = tid; u < 1521; u += 256) {
        int i = u / 39, j = u - i * 39;
        ah[u] = (ah[1521 + i] * ah[u]) * ah[1521 + j];
    }
    __syncthreads();
    if (tid < 39) {
        int cnt = 0;
        for (int m = 0; m < 39; ++m) {
            float v = ah[tid * 39 + m];
            if (v != 0.f && cnt < MAXNZ) {
                alist[tid * MAXNZ + cnt] = make_float2(v, __int_as_float((2 * m) * TLA * 4));
                ++cnt;
            }
        }
        nnzr[tid] = cnt;
    }
    __syncthreads();

    for (int e = tid; e < 78 * TLA; e += 256) {
        int r = e / TLA, tt = e - r * TLA;
        bufA[r * TLA + tt] = x[r * T + ts + tt];
    }
    __syncthreads();

    // f0/f1 + h1 (bufA -> bufB)
    for (int e = tid; e < 78 * TLA; e += 256) {
        int r = e / TLA, tt = e - r * TLA;
        feat[((r >> 1) * TLA + tt) * 8 + (r & 1)] = bufA[r * TLA + tt];
    }
    for (int e = tid; e < 78; e += 256) {
        int r = e, ii = r >> 1, c = r & 1;
        float acc[8];
        #pragma unroll
        for (int u = 0; u < 8; ++u) acc[u] = 0.f;
        int nz = nnzr[ii];
        const float2* lp = &alist[ii * MAXNZ];
        int cg = c * (TLA * 4);
        for (int q = 0; q < nz; ++q) {
            float2 av = lp[q];
            const float* xp = (const float*)((const char*)bufA + (__float_as_int(av.y) + cg));
            float a = av.x;
            float4 x0 = *(const float4*)xp;
            float4 x1 = *(const float4*)(xp + 4);
            acc[0] += a * x0.x; acc[1] += a * x0.y; acc[2] += a * x0.z; acc[3] += a * x0.w;
            acc[4] += a * x1.x; acc[5] += a * x1.y; acc[6] += a * x1.z; acc[7] += a * x1.w;
        }
        float* dp = &bufB[r * TLA];
        *(float4*)dp = *(float4*)&acc[0];
        *(float4*)(dp + 4) = *(float4*)&acc[4];
    }
    __syncthreads();

    // f2/f3 + h2 (bufB -> bufA)
    for (int e = tid; e < 78 * TLA; e += 256) {
        int r = e / TLA, tt = e - r * TLA;
        feat[((r >> 1) * TLA + tt) * 8 + 2 + (r & 1)] = bufB[r * TLA + tt];
    }
    for (int e = tid; e < 78; e += 256) {
        int r = e, ii = r >> 1, c = r & 1;
        float acc[8];
        #pragma unroll
        for (int u = 0; u < 8; ++u) acc[u] = 0.f;
        int nz = nnzr[ii];
        const float2* lp = &alist[ii * MAXNZ];
        int cg = c * (TLA * 4);
        for (int q = 0; q < nz; ++q) {
            float2 av = lp[q];
            const float* xp = (const float*)((const char*)bufB + (__float_as_int(av.y) + cg));
            float a = av.x;
            float4 x0 = *(const float4*)xp;
            float4 x1 = *(const float4*)(xp + 4);
            acc[0] += a * x0.x; acc[1] += a * x0.y; acc[2] += a * x0.z; acc[3] += a * x0.w;
            acc[4] += a * x1.x; acc[5] += a * x1.y; acc[6] += a * x1.z; acc[7] += a * x1.w;
        }
        float* dp = &bufA[r * TLA];
        *(float4*)dp = *(float4*)&acc[0];
        *(float4*)(dp + 4) = *(float4*)&acc[4];
    }
    __syncthreads();

    // f4/f5 + h3 (bufA -> feat[6+c])
    for (int e = tid; e < 78 * TLA; e += 256) {
        int r = e / TLA, tt = e - r * TLA;
        feat[((r >> 1) * TLA + tt) * 8 + 4 + (r & 1)] = bufA[r * TLA + tt];
    }
    for (int e = tid; e < 78; e += 256) {
        int r = e, ii = r >> 1, c = r & 1;
        float acc[8];
        #pragma unroll
        for (int u = 0; u < 8; ++u) acc[u] = 0.f;
        int nz = nnzr[ii];
        const float2* lp = &alist[ii * MAXNZ];
        int cg = c * (TLA * 4);
        for (int q = 0; q < nz; ++q) {
            float2 av = lp[q];
            const float* xp = (const float*)((const char*)bufA + (__float_as_int(av.y) + cg));
            float a = av.x;
            float4 x0 = *(const float4*)xp;
            float4 x1 = *(const float4*)(xp + 4);
            acc[0] += a * x0.x; acc[1] += a * x0.y; acc[2] += a * x0.z; acc[3] += a * x0.w;
            acc[4] += a * x1.x; acc[5] += a * x1.y; acc[6] += a * x1.z; acc[7] += a * x1.w;
        }
        #pragma unroll
        for (int u = 0; u < 8; ++u)
            feat[(ii * TLA + u) * 8 + 6 + c] = acc[u];
    }
    __syncthreads();

    for (int e = tid; e < 39 * TLA * 2; e += 256) {
        int idx = e >> 1, half = e & 1;
        int n = idx / TLA, tt = idx - n * TLA;
        *(float4*)&Fg[((size_t)n * T + ts + tt) * 8 + half * 4] =
            *(const float4*)&feat[idx * 8 + half * 4];
    }

    const int total = 128 * K1N;
    for (int f = bl * 256 + tid; f < total; f += NBLK * 256) {
        int k = f >> 7, jj = f & 127;
        W1t[jj * K1N + k] = packhl(W1[f]);
    }
}

// ============ K2: fused c1-scan + barrier-free reg-MFMA gemm1, 512 threads ===========
// grid (63, 6). Scan: 1 channel/thread (48-step wall). MFMA loop: A from S2 LDS
// (uint read + in-reg spike expand), B direct from L2-resident W1t -> ZERO barriers
// in the K loop; compiler pipelines loads across MFMAs. LDS 24 KB -> 2 blocks/CU.
__global__ __launch_bounds__(512) void scan_gemm1(
        const float* __restrict__ Fg, const float* __restrict__ Wc,
        const float* __restrict__ bc, const short* __restrict__ W1t,
        float* __restrict__ F1p) {
    __shared__ __align__(16) char smem[32 * S2P + 10752];
    unsigned char* S2 = (unsigned char*)smem;      // [32][420] spike bytes
    float* FgL = (float*)(smem + 32 * S2P);        // 7 nodes x ncol x 8 (<=10752 B)

    int tid = threadIdx.x;
    int bx = blockIdx.x, ks = blockIdx.y;
    int t0 = bx * 32;
    int hs = t0 - 16; if (hs < 0) hs = 0;
    int ncol = t0 + 32 - hs;               // 32 (bx=0) or 48
    int k0g = ks * 416;
    int nd0 = k0g >> 6;                    // slice spans exactly 7 nodes
    int kb2 = ks * 832;

    // ---- stage Fg slice: 7 nodes x ncol x 8 ----
    for (int e = tid; e < 7 * ncol * 2; e += 512) {
        int idx = e >> 1, half = e & 1;
        int nl = idx / ncol, cc = idx - nl * ncol;
        int t = hs + cc;
        int gn = nd0 + nl;
        float4 v = make_float4(0.f, 0.f, 0.f, 0.f);
        if (gn < 39 && t < T)
            v = *(const float4*)&Fg[((size_t)gn * T + t) * 8 + half * 4];
        *(float4*)&FgL[(nl * ncol + cc) * 8 + half * 4] = v;
    }
    __syncthreads();

    // ---- scan 416 channels, one per thread (identical FMA order, verified R5) ----
    {
        int cn = tid;
        if (cn < 416) {
            int gk = k0g + cn;
            int nl = (gk >> 6) - nd0;
            int j = gk & 63;
            float wv[8];
            #pragma unroll
            for (int q = 0; q < 8; ++q) wv[q] = Wc[q * 64 + j];
            float bias = bc[j];
            float m = 0.f, s = 0.f;
            const float* fb = &FgL[nl * ncol * 8];
            for (int cc = 0; cc < ncol; ++cc) {
                float4 a0 = *(const float4*)&fb[cc * 8];
                float4 a1 = *(const float4*)&fb[cc * 8 + 4];
                float acc = 0.f;
                acc += wv[0] * a0.x; acc += wv[1] * a0.y;
                acc += wv[2] * a0.z; acc += wv[3] * a0.w;
                acc += wv[4] * a1.x; acc += wv[5] * a1.y;
                acc += wv[6] * a1.z; acc += wv[7] * a1.w;
                float v = acc + bias;
                m = m * 0.2f * (1.f - s) + v;
                s = (m > 0.5f) ? 1.f : 0.f;
                int t = hs + cc;
                if (t >= t0) S2[(t - t0) * S2P + cn] = (unsigned char)(s != 0.f);
            }
        }
    }
    __syncthreads();   // the ONLY barrier before the K loop

    // ---- barrier-free MFMA: 13 chunks x 2 sub; 8 waves x 16 j-cols ----
    int lane = tid & 63, wvi = tid >> 6;   // wvi 0..7
    int j0 = wvi * 16;
    int row = lane & 15, quad = lane >> 4;
    floatx4 a00 = {0.f, 0.f, 0.f, 0.f};
    floatx4 a10 = a00;
    const short* wrow = &W1t[(j0 + row) * K2 + kb2];
    const unsigned char* s2a = &S2[row * S2P];
    const unsigned char* s2b = &S2[(row + 16) * S2P];
    for (int c = 0; c < 13; ++c) {
        #pragma unroll
        for (int sh = 0; sh < 2; ++sh) {
            int kbyte = c * 32 + sh * 16 + quad * 4;
            unsigned ua0 = *(const unsigned*)&s2a[kbyte];
            unsigned ua1 = *(const unsigned*)&s2b[kbyte];
            short8 fa0 = spike8(ua0);
            short8 fa1 = spike8(ua1);
            short8 fb0 = *(const short8*)&wrow[c * 64 + sh * 32 + quad * 8];
            a00 = __builtin_amdgcn_mfma_f32_16x16x32_bf16(fa0, fb0, a00, 0, 0, 0);
            a10 = __builtin_amdgcn_mfma_f32_16x16x32_bf16(fa1, fb0, a10, 0, 0, 0);
        }
    }
    #pragma unroll
    for (int r = 0; r < 4; ++r) {
        int m0 = quad * 4 + r;
        int t = t0 + m0;
        if (t < T)
            F1p[t * 768 + ks * 128 + j0 + row] = a00[r];
        int t2 = t0 + 16 + m0;
        if (t2 < T)
            F1p[t2 * 768 + ks * 128 + j0 + row] = a10[r];
    }
}

// ============ K3: h1 scan (warm 16) + gemm2, t-tile 8, grid 250 (verbatim R4) ========
__global__ __launch_bounds__(256) void h1_gemm2(const float* __restrict__ F1p,
        const float* __restrict__ b1, const float* __restrict__ W2,
        float* __restrict__ G2) {
    __shared__ float AT[128 * 8];
    int tid = threadIdx.x;
    int t0 = blockIdx.x * 8;
    if (tid < 128) {
        int n = tid;
        int hs = t0 - 16; if (hs < 0) hs = 0;
        float b = b1[n];
        float m = 0.f, s = 0.f;
        for (int tg = hs; tg < t0 + 8; tg += 4) {     // lengths 8/24: both %4==0
            float vb[4][6];
            #pragma unroll
            for (int u = 0; u < 4; ++u)
                #pragma unroll
                for (int q = 0; q < 6; ++q)
                    vb[u][q] = F1p[(tg + u) * 768 + q * 128 + n];
            #pragma unroll
            for (int u = 0; u < 4; ++u) {
                float v = 0.f;
                #pragma unroll
                for (int q = 0; q < 6; ++q) v += vb[u][q];
                v += b;
                m = m * 0.2f * (1.f - s) + v;
                s = (m > 0.5f) ? 1.f : 0.f;
                int t = tg + u;
                if (t >= t0) AT[n * 8 + (t - t0)] = s;
            }
        }
    }
    __syncthreads();
    int j = tid;
    float acc[8] = {0.f};
    #pragma unroll 4
    for (int k = 0; k < 128; ++k) {
        float w = W2[k * 256 + j];
        float4 q0 = *(const float4*)&AT[k * 8 + 0];
        float4 q1 = *(const float4*)&AT[k * 8 + 4];
        acc[0] += q0.x * w; acc[1] += q0.y * w; acc[2] += q0.z * w; acc[3] += q0.w * w;
        acc[4] += q1.x * w; acc[5] += q1.y * w; acc[6] += q1.z * w; acc[7] += q1.w * w;
    }
    #pragma unroll
    for (int tt = 0; tt < 8; ++tt) G2[(t0 + tt) * 256 + j] = acc[tt];
}

// ============ K4: h2 (batch-25, warm 25+25) + gemm3 + h3 + out (verbatim R4) =========
__global__ __launch_bounds__(256) void tail(const float* __restrict__ G2,
        const float* __restrict__ b2, const float* __restrict__ W3,
        const float* __restrict__ b3, float* __restrict__ out) {
    __shared__ float w3t[36 * 260];          // [jj][k] pad 260
    __shared__ unsigned char S2[52 * 260];   // [t][n] pad 260
    __shared__ float G3[52 * 36];
    int tid = threadIdx.x;
    int t0 = blockIdx.x * 25;
    int gs = t0 - 25; if (gs < 0) gs = 0;
    int hs = gs - 25; if (hs < 0) hs = 0;
    int L3 = t0 + 25 - gs;                   // 25..50
    #pragma unroll
    for (int u = 0; u < 9; ++u) {
        int f = u * 1024 + tid * 4;
        float4 wq = *(const float4*)&W3[f];
        int k0 = f / 36, j0 = f - k0 * 36;
        float wv[4] = {wq.x, wq.y, wq.z, wq.w};
        #pragma unroll
        for (int q = 0; q < 4; ++q) {
            int k = (j0 + q >= 36) ? k0 + 1 : k0;
            int jj = (j0 + q >= 36) ? (j0 + q - 36) : (j0 + q);
            w3t[jj * 260 + k] = wv[q];
        }
    }
    {
        int n = tid;
        float b = b2[n];
        float m = 0.f, s = 0.f;
        for (int base = hs; base < t0 + 25; base += 25) {
            float vb[25];
            #pragma unroll
            for (int u = 0; u < 25; ++u) vb[u] = G2[(base + u) * 256 + n];
            #pragma unroll
            for (int u = 0; u < 25; ++u) {
                float v = vb[u] + b;
                m = m * 0.2f * (1.f - s) + v;
                s = (m > 0.5f) ? 1.f : 0.f;
                int t = base + u;
                if (t >= gs) S2[(t - gs) * 260 + n] = (unsigned char)(s != 0.f);
            }
        }
    }
    __syncthreads();
    for (int e = tid; e < 36 * 13; e += 256) {
        int jj = e / 13, g = e - (e / 13) * 13;
        int tb = g * 4;
        if (tb >= L3) continue;
        float ac0 = 0.f, ac1 = 0.f, ac2 = 0.f, ac3 = 0.f;
        const unsigned char* r0 = &S2[tb * 260];
        for (int k = 0; k < 256; k += 4) {
            float4 w = *(const float4*)&w3t[jj * 260 + k];
            uchar4 q0 = *(const uchar4*)&r0[k];
            uchar4 q1 = *(const uchar4*)&r0[260 + k];
            uchar4 q2 = *(const uchar4*)&r0[520 + k];
            uchar4 q3 = *(const uchar4*)&r0[780 + k];
            ac0 += (float)q0.x * w.x + (float)q0.y * w.y + (float)q0.z * w.z + (float)q0.w * w.w;
            ac1 += (float)q1.x * w.x + (float)q1.y * w.y + (float)q1.z * w.z + (float)q1.w * w.w;
            ac2 += (float)q2.x * w.x + (float)q2.y * w.y + (float)q2.z * w.z + (float)q2.w * w.w;
            ac3 += (float)q3.x * w.x + (float)q3.y * w.y + (float)q3.z * w.z + (float)q3.w * w.w;
        }
        G3[tb * 36 + jj] = ac0;
        if (tb + 1 < L3) G3[(tb + 1) * 36 + jj] = ac1;
        if (tb + 2 < L3) G3[(tb + 2) * 36 + jj] = ac2;
        if (tb + 3 < L3) G3[(tb + 3) * 36 + jj] = ac3;
    }
    __syncthreads();
    if (tid < 36) {
        int n = tid;
        float b = b3[n];
        float m = 0.f, s = 0.f;
        int cnt = 0;
        for (int t = gs; t < t0 + 25; ++t) {
            float v = G3[(t - gs) * 36 + n] + b;
            m = m * 0.2f * (1.f - s) + v;
            s = (m > 0.5f) ? 1.f : 0.f;
            if (t >= t0) cnt += (s != 0.f) ? 1 : 0;
        }
        atomicAdd(&out[n], (float)cnt * 0.0005f);
    }
}

extern "C" void kernel_launch(void* const* d_in, const int* in_sizes, int n_in,
                              void* d_out, int out_size, void* d_ws, size_t ws_size,
                              hipStream_t stream) {
    const float* x  = (const float*)d_in[0];
    const int*   ei = (const int*)d_in[1];
    const float* Wc = (const float*)d_in[2];
    const float* bc = (const float*)d_in[3];
    const float* W1 = (const float*)d_in[4];
    const float* b1 = (const float*)d_in[5];
    const float* W2 = (const float*)d_in[6];
    const float* b2 = (const float*)d_in[7];
    const float* W3 = (const float*)d_in[8];
    const float* b3 = (const float*)d_in[9];
    float* out = (float*)d_out;

    float* w = (float*)d_ws;
    float* F1p = w;                       w += (size_t)T * 768;    // [t][6][128]
    float* G2  = w;                       w += (size_t)T * 256;
    float* Fg  = w;                       w += (size_t)39 * T * 8; // hop features
    unsigned* W1t = (unsigned*)w;         w += 128 * K1N;

    hops<<<NBLK, 256, 0, stream>>>(x, ei, Fg, W1, W1t, out);
    scan_gemm1<<<dim3(63, 6), 512, 0, stream>>>(Fg, Wc, bc, (const short*)W1t, F1p);
    h1_gemm2<<<250, 256, 0, stream>>>(F1p, b1, W2, G2);
    tail<<<80, 256, 0, stream>>>(G2, b2, W3, b3, out);
}